// Round 12
// baseline (55.161 us; speedup 1.0000x reference)
//
#include <hip/hip_runtime.h>

#define B_TOTAL 4096
#define D 32
#define H 256
#define SPB 16           // samples per block (= MFMA M/N)
#define NW 8             // waves per block
#define HPW 32           // hidden units per wave
#define GAS 36           // gAcc row stride (dwords)

static constexpr float EPS = 0.1f;

typedef __attribute__((ext_vector_type(8))) short short8v;   // 8 x bf16
typedef __attribute__((ext_vector_type(4))) float f32x4;

__device__ __forceinline__ unsigned short bf16rne(float f) {
  unsigned u = __float_as_uint(f);
  u += 0x7FFFu + ((u >> 16) & 1u);
  return (unsigned short)(u >> 16);
}
__device__ __forceinline__ float fromb(unsigned short h) {
  return __uint_as_float(((unsigned)h) << 16);
}
__device__ __forceinline__ void split_rne(float f, unsigned short& hi, unsigned short& lo) {
  hi = bf16rne(f); lo = bf16rne(f - fromb(hi));
}

#define MFMA16(A, Bf, C) __builtin_amdgcn_mfma_f32_16x16x32_bf16((A), (Bf), (C), 0, 0, 0)

// k-permutations (MFMA contracts K in any order as long as A and B agree):
//   kappa(lg*8+j) = lg*4 + (j>>1) + ((j&1)<<4)   [z-pass k=d; = pair-packed slot order]
//   sigma(lg*8+j) = ((j>>2)<<4) + lg*4 + (j&3)   [g-pass k=h; = in-register a layout]

__global__ __launch_bounds__(512, 2) void ma_flow_kernel(
    const float* __restrict__ x_in, const float* __restrict__ logp_in,
    const float* __restrict__ w1, const float* __restrict__ b1,
    const float* __restrict__ w2, float* __restrict__ out)
{
  // triple-buffered atomic g-accumulator [sample][pair-packed d]; buf 2 doubles
  // as the x staging buffer in the preamble (zeroed at stage 1, used at stage 2)
  __shared__ __align__(16) float gAcc[3][SPB][GAS];
  __shared__ float lapB[NW][SPB];

  const int tid = threadIdx.x;
  const int l  = tid & 63;
  const int wv = tid >> 6;       // wave id = 32-h slice
  const int lr = l & 15;         // MFMA index lane: sample (z-out/g-A); d-col (Bg)
  const int lg = l >> 4;         // MFMA k-group
  const int hbase = wv * HPW;

  // ---------------- weight fragments (registers) --------------------------------
  // z-pass A=w1: A[m=h][k=d], h = hbase + tau*16 + lr, k gathered in kappa order
  short8v Bzh[2], Bzl[2];
  float ctau[2];
#pragma unroll
  for (int tau = 0; tau < 2; ++tau) {
    const int h = hbase + tau * 16 + lr;
    float cpart = 0.0f;
    short8v hi, lo;
#pragma unroll
    for (int j = 0; j < 8; ++j) {
      const int dj = lg * 4 + (j >> 1) + ((j & 1) << 4);   // kappa
      float w = w1[dj * H + h];
      cpart = fmaf(w, w, cpart);
      unsigned short hb, lb; split_rne(w, hb, lb);
      hi[j] = (short)hb; lo[j] = (short)lb;
    }
    Bzh[tau] = hi; Bzl[tau] = lo;
    cpart += __shfl_xor(cpart, 16);            // sum the 4 k-groups -> c_h (h by lr)
    cpart += __shfl_xor(cpart, 32);
    ctau[tau] = cpart;
  }
  // per-lane h-tables for the swapped z output: h = hbase + tau*16 + lg*4 + r
  f32x4 b1v[2], w2v[2], w2cv[2];
#pragma unroll
  for (int tau = 0; tau < 2; ++tau)
#pragma unroll
    for (int r = 0; r < 4; ++r) {
      const int hh = hbase + tau * 16 + lg * 4 + r;
      b1v[tau][r] = b1[hh];
      float w2x = w2[hh];
      w2v[tau][r] = w2x;
      w2cv[tau][r] = w2x * __shfl(ctau[tau], lg * 4 + r);  // c redistributed lr->(lg,r)
    }
  // g-pass B=w1^T: B[k=h_local][n=d], d = nu*16 + lr, k gathered in sigma order
  short8v Bgh[2], Bgl[2];
#pragma unroll
  for (int nu = 0; nu < 2; ++nu) {
    const int d = nu * 16 + lr;
    short8v hi, lo;
#pragma unroll
    for (int j = 0; j < 8; ++j) {
      const int hl = ((j >> 2) << 4) + lg * 4 + (j & 3);   // sigma
      float w = w1[d * H + hbase + hl];
      unsigned short hb, lb; split_rne(w, hb, lb);
      hi[j] = (short)hb; lo[j] = (short)lb;
    }
    Bgh[nu] = hi; Bgl[nu] = lo;
  }

  // ---------------- preamble: zero gAcc[0], stage x into gAcc[2] ----------------
  for (int i = tid; i < SPB * GAS; i += 512) gAcc[0][0][i] = 0.0f;
  {
    float xv = x_in[blockIdx.x * (SPB * D) + tid];        // coalesced
    int s = tid >> 5, d = tid & 31;
    gAcc[2][s][((d & 15) << 1) | (d >> 4)] = xv;          // pair-packed layout
  }
  __syncthreads();

  // consumer-lane register state: sample lr, dims kappa(lg*8+j), j=0..7
  float x0r[8], accr[8];
  short8v xh, xl;
  {
    const float* xp = &gAcc[2][lr][lg * 8];
    f32x4 xa = *reinterpret_cast<const f32x4*>(xp);
    f32x4 xb = *reinterpret_cast<const f32x4*>(xp + 4);
    float xv8[8] = {xa.x, xa.y, xa.z, xa.w, xb.x, xb.y, xb.z, xb.w};
#pragma unroll
    for (int j = 0; j < 8; ++j) {
      x0r[j] = xv8[j]; accr[j] = 0.0f;
      unsigned u = __float_as_uint(xv8[j]);
      xh[j] = (short)(u >> 16);
      xl[j] = (short)(__float_as_uint(xv8[j] - __uint_as_float(u & 0xFFFF0000u)) >> 16);
    }
  }
  float lapAcc = 0.0f;     // wa-weighted lap partial (sample lr, this lane's 8 h's)

  // ---------------- 8 RK4 stage evaluations, ONE barrier each -------------------
#pragma unroll 1
  for (int stage = 0; stage < 8; ++stage) {
    const int st = stage & 3;
    const float wa = (st == 0 || st == 3) ? (EPS / 6.0f) : (EPS / 3.0f);
    const float wc = (st == 2) ? EPS : (EPS * 0.5f);
    const int cb = stage % 3;            // accumulate buffer
    const int nb = (stage + 1) % 3;      // zero next buffer (last read 2 stages ago)

    // zero the next accumulation buffer (safe: its readers finished pre BAR_{S-1})
    {
      float* zb = &gAcc[nb][0][0];
      for (int i = tid; i < SPB * GAS; i += 512) zb[i] = 0.0f;
    }

    // -- phase 1: z-MFMAs from register xc frags, sigmoid, aF (all in-register) -
    f32x4 zz[2];
#pragma unroll
    for (int tau = 0; tau < 2; ++tau) {
      f32x4 z = MFMA16(Bzh[tau], xh, b1v[tau]);   // A=w1 (m=h), B=xc (n=sample)
      z = MFMA16(Bzh[tau], xl, z);
      z = MFMA16(Bzl[tau], xh, z);
      zz[tau] = z;
    }
    float q = 0.0f;
    unsigned short ab[2][4];
#pragma unroll
    for (int tau = 0; tau < 2; ++tau)
#pragma unroll
      for (int r = 0; r < 4; ++r) {
        float E = __expf(-zz[tau][r]);
        float t = __builtin_amdgcn_rcpf(1.0f + E);          // sigmoid
        q = fmaf(t * t * E, w2cv[tau][r], q);               // s(1-s) * w2*c
        ab[tau][r] = bf16rne(t * w2v[tau][r]);              // a = s*w2 (bf16)
      }
    lapAcc = fmaf(wa, q, lapAcc);
    short8v aF;                                             // sigma-ordered A-frag
#pragma unroll
    for (int j = 0; j < 8; ++j) aF[j] = (short)ab[j >> 2][j & 3];

    // -- phase 2: g-MFMAs, atomic pre-reduction into gAcc[cb] -------------------
#pragma unroll
    for (int nu = 0; nu < 2; ++nu) {
      f32x4 g = {0.0f, 0.0f, 0.0f, 0.0f};
      g = MFMA16(aF, Bgh[nu], g);
      g = MFMA16(aF, Bgl[nu], g);
#pragma unroll
      for (int r = 0; r < 4; ++r)
        atomicAdd(&gAcc[cb][lg * 4 + r][2 * lr + nu], g[r]);   // ds_add_f32
    }
    __syncthreads();                     // the stage's single barrier

    // -- phase 3: read summed g (2 x b128), replicated in-register update -------
    const float* gp = &gAcc[cb][lr][lg * 8];
    f32x4 ga = *reinterpret_cast<const f32x4*>(gp);
    f32x4 gb = *reinterpret_cast<const f32x4*>(gp + 4);
    float gv[8] = {ga.x, ga.y, ga.z, ga.w, gb.x, gb.y, gb.z, gb.w};
#pragma unroll
    for (int j = 0; j < 8; ++j) {
      accr[j] = fmaf(wa, gv[j], accr[j]);
      float xw;
      if (st < 3) {
        xw = fmaf(wc, gv[j], x0r[j]);
      } else {
        x0r[j] += accr[j]; accr[j] = 0.0f; xw = x0r[j];
      }
      unsigned u = __float_as_uint(xw);
      xh[j] = (short)(u >> 16);
      xl[j] = (short)(__float_as_uint(xw - __uint_as_float(u & 0xFFFF0000u)) >> 16);
    }
  }

  // ---------------- final laplacian reduce (once) --------------------------------
  lapAcc += __shfl_xor(lapAcc, 16);      // sum over the 4 lg groups
  lapAcc += __shfl_xor(lapAcc, 32);
  if (l < 16) lapB[wv][lr] = lapAcc;     // per-wave partial for sample lr
  __syncthreads();

  // ---------------- output --------------------------------------------------------
  // x: state replicated across waves; wave wv stores register slot j=wv
  {
    float vout = x0r[0];
#pragma unroll
    for (int j = 1; j < 8; ++j) if (wv == j) vout = x0r[j];
    const int dslot = lg * 4 + (wv >> 1) + ((wv & 1) << 4);   // kappa(lg*8+wv)
    out[(blockIdx.x * SPB + lr) * D + dslot] = vout;
  }
  if (tid < SPB) {
    float lt = 0.0f;
#pragma unroll
    for (int w = 0; w < NW; ++w) lt += lapB[w][tid];
    out[B_TOTAL * D + blockIdx.x * SPB + tid] = logp_in[blockIdx.x * SPB + tid] - lt;
  }
}

extern "C" void kernel_launch(void* const* d_in, const int* in_sizes, int n_in,
                              void* d_out, int out_size, void* d_ws, size_t ws_size,
                              hipStream_t stream) {
  const float* x    = (const float*)d_in[0];
  const float* logp = (const float*)d_in[1];
  const float* w1   = (const float*)d_in[2];
  const float* b1   = (const float*)d_in[3];
  const float* w2   = (const float*)d_in[4];
  // d_in[5] (b2) shifts u only; it does not affect grad_u or the laplacian.
  float* out = (float*)d_out;

  ma_flow_kernel<<<B_TOTAL / SPB, 512, 0, stream>>>(x, logp, w1, b1, w2, out);
}

// Round 14
// 14.758 us; speedup vs baseline: 3.7377x; 3.7377x over previous
//
#include <hip/hip_runtime.h>

#define B_TOTAL 4096
#define D 32
#define H 256
#define SPB 16           // samples per block (= MFMA M/N)
#define NW 8             // waves per block
#define HPW 32           // hidden units per wave
#define PGS 34           // partG row stride (dwords)
#define XCS 40           // xcH/xcL row stride (u16)
#define WLS 260          // staged-w1 row stride (dwords): bank-spread for gathers

static constexpr float EPS = 0.1f;
static constexpr float LOG2E = 1.44269504088896340736f;

typedef __attribute__((ext_vector_type(8))) short short8v;   // 8 x bf16
typedef __attribute__((ext_vector_type(4))) float f32x4;

__device__ __forceinline__ unsigned short bf16rne(float f) {
  unsigned u = __float_as_uint(f);
  u += 0x7FFFu + ((u >> 16) & 1u);
  return (unsigned short)(u >> 16);
}
__device__ __forceinline__ float fromb(unsigned short h) {
  return __uint_as_float(((unsigned)h) << 16);
}
__device__ __forceinline__ void split_rne(float f, unsigned short& hi, unsigned short& lo) {
  hi = bf16rne(f); lo = bf16rne(f - fromb(hi));
}

#define MFMA16(A, Bf, C) __builtin_amdgcn_mfma_f32_16x16x32_bf16((A), (Bf), (C), 0, 0, 0)

// k-permutations (MFMA contracts K in any order as long as A and B agree):
//   kappa(lg*8+j) = lg*4 + (j>>1) + ((j&1)<<4)   [z-pass k=d; matches xc pair layout]
//   sigma(lg*8+j) = ((j>>2)<<4) + lg*4 + (j&3)   [g-pass k=h; matches in-register a layout]

__global__ __launch_bounds__(512, 2) void ma_flow_kernel(
    const float* __restrict__ x_in, const float* __restrict__ logp_in,
    const float* __restrict__ w1, const float* __restrict__ b1,
    const float* __restrict__ w2, float* __restrict__ out)
{
  __shared__ __align__(16) float wL[D][WLS];                 // staged w1 (preamble only)
  __shared__ __align__(16) float partG[NW][SPB][PGS];        // per-wave partial g (paired cols)
  __shared__ __align__(16) unsigned short xcH[SPB][XCS];     // xc hi-bf16, pair layout
  __shared__ __align__(16) unsigned short xcL[SPB][XCS];     // xc lo-bf16, pair layout

  const int tid = threadIdx.x;
  const int l  = tid & 63;
  const int wv = tid >> 6;       // wave id = 32-h slice
  const int lr = l & 15;         // MFMA index lane: sample (z-out/g-A); d-col (Bg)
  const int lg = l >> 4;         // MFMA k-group
  const int hbase = wv * HPW;
  const int s_own = tid >> 5;    // owned sample
  const int d_own = tid & 31;    // owned dim
  const int xci = ((d_own & 15) << 1) | (d_own >> 4);   // u16 index, xc pair layout
  const int posd = xci;                                 // partG column of owned dim

  // ---------------- stage w1 into LDS (coalesced), then gather fragments --------
  for (int i = tid; i < D * H; i += 512)
    wL[i >> 8][i & 255] = w1[i];                        // coalesced
  __syncthreads();

  // z-pass A=w1*log2e: A[m=h][k=d], h = hbase + tau*16 + lr, kappa k-order
  short8v Bzh[2], Bzl[2];
  float ctau[2];
#pragma unroll
  for (int tau = 0; tau < 2; ++tau) {
    const int h = hbase + tau * 16 + lr;
    float cpart = 0.0f;
    short8v hi, lo;
#pragma unroll
    for (int j = 0; j < 8; ++j) {
      const int dj = lg * 4 + (j >> 1) + ((j & 1) << 4);   // kappa
      float w = wL[dj][h];
      cpart = fmaf(w, w, cpart);                           // c_h from TRUE w
      unsigned short hb, lb; split_rne(w * LOG2E, hb, lb); // scaled for exp2
      hi[j] = (short)hb; lo[j] = (short)lb;
    }
    Bzh[tau] = hi; Bzl[tau] = lo;
    cpart += __shfl_xor(cpart, 16);            // sum the 4 k-groups -> c_h (h by lr)
    cpart += __shfl_xor(cpart, 32);
    ctau[tau] = cpart;
  }
  // per-lane h-tables for the swapped z output: h = hbase + tau*16 + lg*4 + r
  f32x4 b1v[2], w2v[2], w2cv[2];
#pragma unroll
  for (int tau = 0; tau < 2; ++tau)
#pragma unroll
    for (int r = 0; r < 4; ++r) {
      const int hh = hbase + tau * 16 + lg * 4 + r;
      b1v[tau][r] = b1[hh] * LOG2E;                        // scaled bias
      float w2x = w2[hh];
      w2v[tau][r] = w2x;
      w2cv[tau][r] = w2x * __shfl(ctau[tau], lg * 4 + r);  // c redistributed lr->(lg,r)
    }
  // g-pass B=w1^T (TRUE weights): B[k=h][n=d], d = nu*16 + lr, sigma k-order
  short8v Bgh[2], Bgl[2];
#pragma unroll
  for (int nu = 0; nu < 2; ++nu) {
    const int d = nu * 16 + lr;
    short8v hi, lo;
#pragma unroll
    for (int j = 0; j < 8; ++j) {
      const int hl = ((j >> 2) << 4) + lg * 4 + (j & 3);   // sigma
      float w = wL[d][hbase + hl];
      unsigned short hb, lb; split_rne(w, hb, lb);
      hi[j] = (short)hb; lo[j] = (short)lb;
    }
    Bgh[nu] = hi; Bgl[nu] = lo;
  }

  // ---------------- state init: thread owns (s_own, d_own) ----------------------
  float x0r = x_in[blockIdx.x * (SPB * D) + tid];   // coalesced
  float accr = 0.0f;
  {
    unsigned u = __float_as_uint(x0r);
    xcH[s_own][xci] = (unsigned short)(u >> 16);
    float res = x0r - __uint_as_float(u & 0xFFFF0000u);   // exact
    xcL[s_own][xci] = (unsigned short)(__float_as_uint(res) >> 16);
  }
  float lp = (tid < SPB) ? logp_in[blockIdx.x * SPB + tid] : 0.0f;
  float lapAcc = 0.0f;     // wa-weighted lap partial for sample lr (this lane's 8 h's)
  __syncthreads();

  // ---------------- 8 RK4 stage evaluations -------------------------------------
#pragma unroll 1
  for (int stage = 0; stage < 8; ++stage) {
    const int st = stage & 3;
    const float wa = (st == 0 || st == 3) ? (EPS / 6.0f) : (EPS / 3.0f);
    const float wc = (st == 2) ? EPS : (EPS * 0.5f);

    // -- phase 1: swapped z-MFMAs (D[m=h][n=sample]) + sigmoid, in-register -----
    short8v xh = *reinterpret_cast<const short8v*>(&xcH[lr][lg * 8]);
    short8v xl = *reinterpret_cast<const short8v*>(&xcL[lr][lg * 8]);

    f32x4 zz[2];
#pragma unroll
    for (int tau = 0; tau < 2; ++tau) {
      f32x4 z = MFMA16(Bzh[tau], xh, b1v[tau]);   // A=w1 (m=h), B=xc (n=sample)
      z = MFMA16(Bzh[tau], xl, z);
      z = MFMA16(Bzl[tau], xh, z);
      zz[tau] = z;                                 // z' = z * log2e
    }
    float q = 0.0f;
    unsigned short ab[2][4];
#pragma unroll
    for (int tau = 0; tau < 2; ++tau)
#pragma unroll
      for (int r = 0; r < 4; ++r) {
        float E = __builtin_amdgcn_exp2f(-zz[tau][r]);      // 2^(-z') = e^(-z)
        float t = __builtin_amdgcn_rcpf(1.0f + E);          // sigmoid
        q = fmaf(t * t * E, w2cv[tau][r], q);               // s(1-s) * w2*c
        ab[tau][r] = bf16rne(t * w2v[tau][r]);              // a = s*w2 (bf16)
      }
    lapAcc = fmaf(wa, q, lapAcc);
    short8v aF;                                             // sigma-ordered A-frag
#pragma unroll
    for (int j = 0; j < 8; ++j) aF[j] = (short)ab[j >> 2][j & 3];

    // -- phase 2: g-MFMAs straight from registers, paired partG writes ----------
    f32x4 gg[2];
#pragma unroll
    for (int nu = 0; nu < 2; ++nu) {
      f32x4 g = {0.0f, 0.0f, 0.0f, 0.0f};
      g = MFMA16(aF, Bgh[nu], g);
      g = MFMA16(aF, Bgl[nu], g);
      gg[nu] = g;
    }
#pragma unroll
    for (int r = 0; r < 4; ++r)
      *reinterpret_cast<float2*>(&partG[wv][lg * 4 + r][2 * lr]) =
          make_float2(gg[0][r], gg[1][r]);       // cols 2*lr+nu
    __syncthreads();                     // barrier 1: partG ready

    // -- phase 3: owner-thread reduce, state update, pair-packed xc write -------
    float p0 = partG[0][s_own][posd], p1 = partG[1][s_own][posd];
    float p2 = partG[2][s_own][posd], p3 = partG[3][s_own][posd];
    float p4 = partG[4][s_own][posd], p5 = partG[5][s_own][posd];
    float p6 = partG[6][s_own][posd], p7 = partG[7][s_own][posd];
    float gsum = ((p0 + p1) + (p2 + p3)) + ((p4 + p5) + (p6 + p7));
    accr = fmaf(wa, gsum, accr);
    float xw;
    if (st < 3) {
      xw = fmaf(wc, gsum, x0r);
    } else {
      x0r += accr; accr = 0.0f; xw = x0r;
    }
    {
      unsigned u = __float_as_uint(xw);
      xcH[s_own][xci] = (unsigned short)(u >> 16);
      float res = xw - __uint_as_float(u & 0xFFFF0000u);    // exact
      xcL[s_own][xci] = (unsigned short)(__float_as_uint(res) >> 16);
    }
    __syncthreads();                     // barrier 2: xc ready (+ partG WAR)
  }

  // ---------------- final laplacian reduce (once) --------------------------------
  lapAcc += __shfl_xor(lapAcc, 16);      // sum over the 4 lg groups
  lapAcc += __shfl_xor(lapAcc, 32);
  if (l < 16) partG[wv][lr][0] = lapAcc; // per-wave partial for sample lr
  __syncthreads();

  // ---------------- output --------------------------------------------------------
  out[blockIdx.x * (SPB * D) + tid] = x0r;             // coalesced
  if (tid < SPB) {
    float lt = 0.0f;
#pragma unroll
    for (int w = 0; w < NW; ++w) lt += partG[w][tid][0];
    out[B_TOTAL * D + blockIdx.x * SPB + tid] = lp - lt;
  }
}

extern "C" void kernel_launch(void* const* d_in, const int* in_sizes, int n_in,
                              void* d_out, int out_size, void* d_ws, size_t ws_size,
                              hipStream_t stream) {
  const float* x    = (const float*)d_in[0];
  const float* logp = (const float*)d_in[1];
  const float* w1   = (const float*)d_in[2];
  const float* b1   = (const float*)d_in[3];
  const float* w2   = (const float*)d_in[4];
  // d_in[5] (b2) shifts u only; it does not affect grad_u or the laplacian.
  float* out = (float*)d_out;

  ma_flow_kernel<<<B_TOTAL / SPB, 512, 0, stream>>>(x, logp, w1, b1, w2, out);
}